// Round 3
// baseline (834.549 us; speedup 1.0000x reference)
//
#include <hip/hip_runtime.h>
#include <hip/hip_cooperative_groups.h>

namespace cg = cooperative_groups;

#define N_NODES 100000
#define E_EDGES 1600000
#define DIM     128

// Binning geometry: coarse bucket = 256 nodes (dst>>8), 391 real buckets, pad 512.
#define NB1     391            // level-1 chunks (4096 edges each)
#define NBINS   512            // padded bucket count (actual 391)
#define NBH     (NBINS * NB1)  // 200192 bin-major [bin][chunk] histogram entries
#define HS_BLOCKS 196          // ceil(NBH/1024) scan stage-1 blocks

// Workspace layout (bytes), total ~65.3 MiB:
#define HB_OFF    0            // h packed bf16: N*64 u32 = 25,600,000
#define AGGB_OFF  25600000     // mean-agg packed bf16: N*64 u32 = 25,600,000
#define WTB_OFF   51200000     // WcatT bf16 B-fragment layout: 16384 u32 = 65,536
#define OFFS_OFF  51265536     // N+1 int (padded to 400,064)
#define BH_OFF    51665600     // NBH ints (padded to 802,816)
#define BSUM_OFF  52468416     // HS_BLOCKS ints (padded to 1024)
#define BIN_OFF   52469440     // E ints = 6,400,000
#define SRC_OFF   58869440     // E ints = 6,400,000 -> end 65,269,440

typedef __attribute__((ext_vector_type(8))) short short8;
typedef __attribute__((ext_vector_type(4))) float floatx4;

// ---------- bf16 pack/unpack (RNE) ----------
__device__ __forceinline__ unsigned bf16pack(float a, float b) {
  unsigned ua = __float_as_uint(a); ua += 0x7fffu + ((ua >> 16) & 1u);
  unsigned ub = __float_as_uint(b); ub += 0x7fffu + ((ub >> 16) & 1u);
  return (ua >> 16) | (ub & 0xffff0000u);
}
__device__ __forceinline__ float2 bf16unpack(unsigned p) {
  return make_float2(__uint_as_float(p << 16), __uint_as_float(p & 0xffff0000u));
}

// ================= single cooperative mega-kernel =================
// Phases (verbatim R2 bodies, grid-strided):
//  P0  LN+ReLU->hb | weight pack | level-1 histogram      (independent, no sync)
//  P1  hscan stage 1          P2  hscan stage 2
//  P3  level-1 scatter        P4  per-bucket CSR
//  P5  gather+mean->aggb      P6  MFMA GEMM->out
__global__ __launch_bounds__(256, 4) void k_mega(
    const float* __restrict__ x, const int* __restrict__ ei,
    const float* __restrict__ lw, const float* __restrict__ lb,
    const float* __restrict__ Wl, const float* __restrict__ bl,
    const float* __restrict__ Wr, float* __restrict__ out,
    char* __restrict__ ws) {
  unsigned* hb     = (unsigned*)(ws + HB_OFF);
  unsigned* aggb   = (unsigned*)(ws + AGGB_OFF);
  unsigned* wtb    = (unsigned*)(ws + WTB_OFF);
  int*      offs   = (int*)(ws + OFFS_OFF);
  int*      bh     = (int*)(ws + BH_OFF);
  int*      bsum   = (int*)(ws + BSUM_OFF);
  int*      binned = (int*)(ws + BIN_OFF);
  int*      srcidx = (int*)(ws + SRC_OFF);

  cg::grid_group grid = cg::this_grid();
  __shared__ int smem[768];
  const int t    = threadIdx.x;
  const int blk  = blockIdx.x;
  const int gdim = gridDim.x;
  const int lane = t & 63;
  const int wv   = t >> 6;

  // ---------------- P0: LN+ReLU, weight pack, level-1 histogram --------------
  for (int g = blk; g < N_NODES / 4; g += gdim) {
    int row = g * 4 + wv;
    float2 v = ((const float2*)(x + (size_t)row * DIM))[lane];
    float sAcc = v.x + v.y;
    float qAcc = v.x * v.x + v.y * v.y;
    #pragma unroll
    for (int off = 32; off > 0; off >>= 1) {
      sAcc += __shfl_xor(sAcc, off);
      qAcc += __shfl_xor(qAcc, off);
    }
    float mu  = sAcc * (1.0f / 128.0f);
    float var = qAcc * (1.0f / 128.0f) - mu * mu;
    float rs  = rsqrtf(var + 1e-5f);
    float2 w = ((const float2*)lw)[lane];
    float2 b = ((const float2*)lb)[lane];
    float ox = fmaxf((v.x - mu) * rs * w.x + b.x, 0.0f);
    float oy = fmaxf((v.y - mu) * rs * w.y + b.y, 0.0f);
    hb[(size_t)row * 64 + lane] = bf16pack(ox, oy);
  }
  {
    int gid = blk * 256 + t;
    if (gid < 16384) {
      int j2 = gid & 3;
      int q  = (gid >> 2) & 3;
      int c  = (gid >> 4) & 127;
      int kb = gid >> 11;
      int k0 = kb * 32 + q * 8 + j2 * 2;
      int k1 = k0 + 1;
      float v0 = (k0 < 128) ? Wl[c * 128 + k0] : Wr[c * 128 + (k0 - 128)];
      float v1 = (k1 < 128) ? Wl[c * 128 + k1] : Wr[c * 128 + (k1 - 128)];
      wtb[gid] = bf16pack(v0, v1);
    }
  }
  for (int ch = blk; ch < NB1; ch += gdim) {
    smem[t] = 0; smem[t + 256] = 0;
    __syncthreads();
    const int4* d4p = (const int4*)(ei + E_EDGES);
    #pragma unroll
    for (int u = 0; u < 4; ++u) {
      int i4 = ch * 1024 + u * 256 + t;
      if (i4 < E_EDGES / 4) {
        int4 d = d4p[i4];
        atomicAdd(&smem[d.x >> 8], 1);
        atomicAdd(&smem[d.y >> 8], 1);
        atomicAdd(&smem[d.z >> 8], 1);
        atomicAdd(&smem[d.w >> 8], 1);
      }
    }
    __syncthreads();
    bh[t * NB1 + ch] = smem[t];
    bh[(t + 256) * NB1 + ch] = smem[t + 256];
    __syncthreads();
  }
  grid.sync();

  // ---------------- P1: scan stage 1 over bh ---------------------------------
  if (blk < HS_BLOCKS) {
    int base = blk * 1024 + t * 4;
    int a0 = (base + 0 < NBH) ? bh[base + 0] : 0;
    int a1 = (base + 1 < NBH) ? bh[base + 1] : 0;
    int a2 = (base + 2 < NBH) ? bh[base + 2] : 0;
    int a3 = (base + 3 < NBH) ? bh[base + 3] : 0;
    smem[t] = a0 + a1 + a2 + a3;
    __syncthreads();
    #pragma unroll
    for (int off = 1; off < 256; off <<= 1) {
      int xv = (t >= off) ? smem[t - off] : 0;
      __syncthreads();
      smem[t] += xv;
      __syncthreads();
    }
    int excl = (t > 0) ? smem[t - 1] : 0;
    if (t == 255) bsum[blk] = smem[255];
    if (base + 0 < NBH) bh[base + 0] = excl;
    if (base + 1 < NBH) bh[base + 1] = excl + a0;
    if (base + 2 < NBH) bh[base + 2] = excl + a0 + a1;
    if (base + 3 < NBH) bh[base + 3] = excl + a0 + a1 + a2;
  }
  grid.sync();

  // ---------------- P2: scan stage 2 (add block bases) -----------------------
  if (blk < HS_BLOCKS) {
    smem[t] = (t < HS_BLOCKS) ? bsum[t] : 0;
    __syncthreads();
    #pragma unroll
    for (int off = 1; off < 256; off <<= 1) {
      int xv = (t >= off) ? smem[t - off] : 0;
      __syncthreads();
      smem[t] += xv;
      __syncthreads();
    }
    int add = (blk > 0) ? smem[blk - 1] : 0;
    #pragma unroll
    for (int u = 0; u < 4; ++u) {
      int i = blk * 1024 + t * 4 + u;
      if (i < NBH) bh[i] += add;
    }
  }
  grid.sync();

  // ---------------- P3: level-1 scatter into coarse buckets ------------------
  for (int ch = blk; ch < NB1; ch += gdim) {
    smem[t] = bh[t * NB1 + ch];
    smem[t + 256] = bh[(t + 256) * NB1 + ch];
    __syncthreads();
    const int4* s4p = (const int4*)ei;
    const int4* d4p = (const int4*)(ei + E_EDGES);
    #pragma unroll
    for (int u = 0; u < 4; ++u) {
      int i4 = ch * 1024 + u * 256 + t;
      if (i4 < E_EDGES / 4) {
        int4 sv = s4p[i4];
        int4 dv = d4p[i4];
        int p0 = atomicAdd(&smem[dv.x >> 8], 1);
        int p1 = atomicAdd(&smem[dv.y >> 8], 1);
        int p2 = atomicAdd(&smem[dv.z >> 8], 1);
        int p3 = atomicAdd(&smem[dv.w >> 8], 1);
        binned[p0] = sv.x | ((dv.x & 255) << 20);
        binned[p1] = sv.y | ((dv.y & 255) << 20);
        binned[p2] = sv.z | ((dv.z & 255) << 20);
        binned[p3] = sv.w | ((dv.w & 255) << 20);
      }
    }
    __syncthreads();
  }
  grid.sync();

  // ---------------- P4: per-bucket exact CSR ---------------------------------
  for (int bin = blk; bin < NB1; bin += gdim) {
    int* h   = smem;
    int* sc  = smem + 256;
    int* cur = smem + 512;
    int base = bh[bin * NB1];
    int end  = bh[(bin + 1) * NB1];
    h[t] = 0;
    __syncthreads();
    for (int i = base + t; i < end; i += 256)
      atomicAdd(&h[(binned[i] >> 20) & 255], 1);
    __syncthreads();
    sc[t] = h[t];
    __syncthreads();
    #pragma unroll
    for (int off = 1; off < 256; off <<= 1) {
      int xv = (t >= off) ? sc[t - off] : 0;
      __syncthreads();
      sc[t] += xv;
      __syncthreads();
    }
    int excl = (t > 0) ? sc[t - 1] : 0;
    cur[t] = excl;
    int node = bin * 256 + t;
    if (node < N_NODES) offs[node] = base + excl;
    if (node == N_NODES) offs[N_NODES] = E_EDGES;
    __syncthreads();
    for (int i = base + t; i < end; i += 256) {
      int p = binned[i];
      int r = atomicAdd(&cur[(p >> 20) & 255], 1);
      srcidx[base + r] = p & 0xFFFFF;
    }
    __syncthreads();
  }
  grid.sync();

  // ---------------- P5: gather + mean -> aggb --------------------------------
  for (int g = blk; g < N_NODES / 8; g += gdim) {
    int n0 = g * 8 + wv * 2;
    int n1 = n0 + 1;
    int b0 = __builtin_amdgcn_readfirstlane(offs[n0]);
    int e0 = __builtin_amdgcn_readfirstlane(offs[n0 + 1]);
    int b1 = __builtin_amdgcn_readfirstlane(offs[n1]);
    int e1 = __builtin_amdgcn_readfirstlane(offs[n1 + 1]);
    int m0 = e0 - b0, m1 = e1 - b1;
    int c  = (m0 < m1 ? m0 : m1) & ~7;

    float ax0 = 0.0f, ay0 = 0.0f, ax1 = 0.0f, ay1 = 0.0f;

    for (int j = 0; j < c; j += 8) {
      unsigned p0[8], p1[8];
      #pragma unroll
      for (int i = 0; i < 8; ++i) {
        int s0 = srcidx[b0 + j + i];
        int s1 = srcidx[b1 + j + i];
        p0[i] = hb[(size_t)s0 * 64 + lane];
        p1[i] = hb[(size_t)s1 * 64 + lane];
      }
      #pragma unroll
      for (int i = 0; i < 8; ++i) {
        float2 v0 = bf16unpack(p0[i]);
        float2 v1 = bf16unpack(p1[i]);
        ax0 += v0.x; ay0 += v0.y;
        ax1 += v1.x; ay1 += v1.y;
      }
    }
    for (int j = b0 + c; j < e0; ) {
      int rem = e0 - j;
      if (rem >= 8) {
        unsigned p[8];
        #pragma unroll
        for (int i = 0; i < 8; ++i) p[i] = hb[(size_t)srcidx[j + i] * 64 + lane];
        #pragma unroll
        for (int i = 0; i < 8; ++i) { float2 v = bf16unpack(p[i]); ax0 += v.x; ay0 += v.y; }
        j += 8;
      } else {
        float2 v = bf16unpack(hb[(size_t)srcidx[j] * 64 + lane]);
        ax0 += v.x; ay0 += v.y;
        ++j;
      }
    }
    for (int j = b1 + c; j < e1; ) {
      int rem = e1 - j;
      if (rem >= 8) {
        unsigned p[8];
        #pragma unroll
        for (int i = 0; i < 8; ++i) p[i] = hb[(size_t)srcidx[j + i] * 64 + lane];
        #pragma unroll
        for (int i = 0; i < 8; ++i) { float2 v = bf16unpack(p[i]); ax1 += v.x; ay1 += v.y; }
        j += 8;
      } else {
        float2 v = bf16unpack(hb[(size_t)srcidx[j] * 64 + lane]);
        ax1 += v.x; ay1 += v.y;
        ++j;
      }
    }

    float inv0 = 1.0f / fmaxf((float)m0, 1.0f);
    float inv1 = 1.0f / fmaxf((float)m1, 1.0f);
    aggb[(size_t)n0 * 64 + lane] = bf16pack(ax0 * inv0, ay0 * inv0);
    aggb[(size_t)n1 * 64 + lane] = bf16pack(ax1 * inv1, ay1 * inv1);
  }
  grid.sync();

  // ---------------- P6: bf16 MFMA GEMM: out = [aggb|hb] @ WcatT^T + b_l ------
  for (int g = blk; g < (N_NODES + 63) / 64; g += gdim) {
    int m = lane & 15;
    int q = lane >> 4;
    int r0 = g * 64 + wv * 16;
    int rowA = r0 + m;
    if (rowA > N_NODES - 1) rowA = N_NODES - 1;

    const uint4* ar = (const uint4*)(aggb + (size_t)rowA * 64);
    const uint4* hr = (const uint4*)(hb + (size_t)rowA * 64);
    short8 afrag[8];
    #pragma unroll
    for (int kb = 0; kb < 4; ++kb) {
      uint4 u = ar[kb * 4 + q];
      afrag[kb] = *(short8*)&u;
    }
    #pragma unroll
    for (int kb = 0; kb < 4; ++kb) {
      uint4 u = hr[kb * 4 + q];
      afrag[kb + 4] = *(short8*)&u;
    }

    const uint4* b4 = (const uint4*)wtb;
    #pragma unroll
    for (int ct = 0; ct < 8; ++ct) {
      int c = ct * 16 + m;
      floatx4 acc = {0.0f, 0.0f, 0.0f, 0.0f};
      #pragma unroll
      for (int kb = 0; kb < 8; ++kb) {
        uint4 u = b4[kb * 512 + c * 4 + q];
        short8 bfrag = *(short8*)&u;
        acc = __builtin_amdgcn_mfma_f32_16x16x32_bf16(afrag[kb], bfrag, acc, 0, 0, 0);
      }
      float bias = bl[c];
      #pragma unroll
      for (int reg = 0; reg < 4; ++reg) {
        int r = r0 + q * 4 + reg;
        if (r < N_NODES) out[(size_t)r * DIM + c] = acc[reg] + bias;
      }
    }
  }
}

extern "C" void kernel_launch(void* const* d_in, const int* in_sizes, int n_in,
                              void* d_out, int out_size, void* d_ws, size_t ws_size,
                              hipStream_t stream) {
  const float* x  = (const float*)d_in[0];
  const int*   ei = (const int*)d_in[1];   // [2, E] int32
  const float* lw = (const float*)d_in[2];
  const float* lb = (const float*)d_in[3];
  const float* Wl = (const float*)d_in[4];
  const float* bl = (const float*)d_in[5];
  const float* Wr = (const float*)d_in[6];
  float* out = (float*)d_out;
  char* ws = (char*)d_ws;

  // Cooperative grid size: blocks/CU from occupancy API (no stream ops; capture-safe).
  static int grid = 0;
  if (grid == 0) {
    int maxB = 0;
    (void)hipOccupancyMaxActiveBlocksPerMultiprocessor(&maxB, k_mega, 256, 0);
    if (maxB < 1) maxB = 1;
    grid = 256 * maxB;
    if (grid > 1024) grid = 1024;   // 4 blocks/CU target (launch_bounds(256,4))
  }

  void* args[9];
  args[0] = (void*)&x;  args[1] = (void*)&ei; args[2] = (void*)&lw;
  args[3] = (void*)&lb; args[4] = (void*)&Wl; args[5] = (void*)&bl;
  args[6] = (void*)&Wr; args[7] = (void*)&out; args[8] = (void*)&ws;
  hipLaunchCooperativeKernel((void*)k_mega, dim3(grid), dim3(256), args, 0, stream);
}

// Round 4
// 261.726 us; speedup vs baseline: 3.1886x; 3.1886x over previous
//
#include <hip/hip_runtime.h>

#define N_NODES 100000
#define E_EDGES 1600000
#define DIM     128

// Binning geometry: coarse bucket = 256 nodes (dst>>8), 391 real buckets, pad 512.
#define NB1     391            // level-1 chunks (4096 edges each)
#define NBINS   512            // padded bucket count (actual 391)
#define NBH     (NBINS * NB1)  // 200192 bin-major [bin][chunk] histogram entries
#define HS_BLOCKS 196          // ceil(NBH/1024) scan stage-1 blocks

// Workspace layout (bytes), total ~65.3 MiB:
#define HB_OFF    0            // h packed bf16: N*64 u32 = 25,600,000
#define WTB_OFF   25600000     // WcatT bf16 B-fragment layout: 16384 u32 = 65,536
#define OFFS_OFF  25665536     // N+1 int (padded to 400,064)
#define BH_OFF    26065600     // NBH ints (padded to 802,816)
#define BSUM_OFF  26868416     // HS_BLOCKS ints (padded to 1024)
#define BIN_OFF   26869440     // E ints = 6,400,000
#define SRC_OFF   33269440     // E ints = 6,400,000 -> end 39,669,440

typedef __attribute__((ext_vector_type(8))) short short8;
typedef __attribute__((ext_vector_type(4))) float floatx4;

// ---------- bf16 pack/unpack (RNE) ----------
__device__ __forceinline__ unsigned bf16pack(float a, float b) {
  unsigned ua = __float_as_uint(a); ua += 0x7fffu + ((ua >> 16) & 1u);
  unsigned ub = __float_as_uint(b); ub += 0x7fffu + ((ub >> 16) & 1u);
  return (ua >> 16) | (ub & 0xffff0000u);
}
__device__ __forceinline__ float2 bf16unpack(unsigned p) {
  return make_float2(__uint_as_float(p << 16), __uint_as_float(p & 0xffff0000u));
}

// ------------- prep: LayerNorm+ReLU -> hb, weight pack, level-1 histogram ----
__global__ __launch_bounds__(256) void k_prep(const float* __restrict__ x,
                                              const float* __restrict__ lw,
                                              const float* __restrict__ lb,
                                              const float* __restrict__ Wl,
                                              const float* __restrict__ Wr,
                                              const int* __restrict__ ei,
                                              unsigned* __restrict__ hb,
                                              unsigned* __restrict__ wtb,
                                              int* __restrict__ bh) {
  int gid = blockIdx.x * 256 + threadIdx.x;
  int t = threadIdx.x;

  // --- LN+ReLU ---
  {
    int row  = blockIdx.x * 4 + (t >> 6);
    int lane = t & 63;
    float2 v = ((const float2*)(x + (size_t)row * DIM))[lane];
    float s  = v.x + v.y;
    float sq = v.x * v.x + v.y * v.y;
    #pragma unroll
    for (int off = 32; off > 0; off >>= 1) {
      s  += __shfl_xor(s, off);
      sq += __shfl_xor(sq, off);
    }
    float mu  = s * (1.0f / 128.0f);
    float var = sq * (1.0f / 128.0f) - mu * mu;
    float rs  = rsqrtf(var + 1e-5f);
    float2 w = ((const float2*)lw)[lane];
    float2 b = ((const float2*)lb)[lane];
    float ox = fmaxf((v.x - mu) * rs * w.x + b.x, 0.0f);
    float oy = fmaxf((v.y - mu) * rs * w.y + b.y, 0.0f);
    hb[(size_t)row * 64 + lane] = bf16pack(ox, oy);
  }

  // --- weight pack (bf16, B-fragment layout) ---
  if (gid < 16384) {
    int j2 = gid & 3;
    int q  = (gid >> 2) & 3;
    int c  = (gid >> 4) & 127;
    int kb = gid >> 11;
    int k0 = kb * 32 + q * 8 + j2 * 2;
    int k1 = k0 + 1;
    float v0 = (k0 < 128) ? Wl[c * 128 + k0] : Wr[c * 128 + (k0 - 128)];
    float v1 = (k1 < 128) ? Wl[c * 128 + k1] : Wr[c * 128 + (k1 - 128)];
    wtb[gid] = bf16pack(v0, v1);
  }

  // --- level-1 histogram (block-uniform branch; LDS atomics) ---
  if (blockIdx.x < NB1) {
    __shared__ int h[NBINS];
    h[t] = 0; h[t + 256] = 0;
    __syncthreads();
    const int4* d4p = (const int4*)(ei + E_EDGES);
    #pragma unroll
    for (int u = 0; u < 4; ++u) {
      int i4 = blockIdx.x * 1024 + u * 256 + t;
      if (i4 < E_EDGES / 4) {
        int4 d = d4p[i4];
        atomicAdd(&h[d.x >> 8], 1);
        atomicAdd(&h[d.y >> 8], 1);
        atomicAdd(&h[d.z >> 8], 1);
        atomicAdd(&h[d.w >> 8], 1);
      }
    }
    __syncthreads();
    bh[t * NB1 + blockIdx.x] = h[t];
    bh[(t + 256) * NB1 + blockIdx.x] = h[t + 256];
  }
}

// ---------------- scan stage 1 over bh (in-place, 1024 elems/block) ----------
__global__ __launch_bounds__(256) void k_hscan1(int* __restrict__ bh,
                                                int* __restrict__ bsum) {
  __shared__ int s[256];
  int t = threadIdx.x;
  int base = blockIdx.x * 1024 + t * 4;
  int a0 = (base + 0 < NBH) ? bh[base + 0] : 0;
  int a1 = (base + 1 < NBH) ? bh[base + 1] : 0;
  int a2 = (base + 2 < NBH) ? bh[base + 2] : 0;
  int a3 = (base + 3 < NBH) ? bh[base + 3] : 0;
  s[t] = a0 + a1 + a2 + a3;
  __syncthreads();
  #pragma unroll
  for (int off = 1; off < 256; off <<= 1) {
    int x = (t >= off) ? s[t - off] : 0;
    __syncthreads();
    s[t] += x;
    __syncthreads();
  }
  int excl = (t > 0) ? s[t - 1] : 0;
  if (t == 255) bsum[blockIdx.x] = s[255];
  if (base + 0 < NBH) bh[base + 0] = excl;
  if (base + 1 < NBH) bh[base + 1] = excl + a0;
  if (base + 2 < NBH) bh[base + 2] = excl + a0 + a1;
  if (base + 3 < NBH) bh[base + 3] = excl + a0 + a1 + a2;
}

// ---------------- scan stage 2: add block bases (196 <= 256 lanes) -----------
__global__ __launch_bounds__(256) void k_hscan2(int* __restrict__ bh,
                                                const int* __restrict__ bsum) {
  __shared__ int s[256];
  int t = threadIdx.x;
  s[t] = (t < HS_BLOCKS) ? bsum[t] : 0;
  __syncthreads();
  #pragma unroll
  for (int off = 1; off < 256; off <<= 1) {
    int x = (t >= off) ? s[t - off] : 0;
    __syncthreads();
    s[t] += x;
    __syncthreads();
  }
  int blk = blockIdx.x;
  int add = (blk > 0) ? s[blk - 1] : 0;
  #pragma unroll
  for (int u = 0; u < 4; ++u) {
    int i = blk * 1024 + t * 4 + u;
    if (i < NBH) bh[i] += add;
  }
}

// ---------------- level-1 scatter: edges -> coarse buckets (LDS cursors) -----
__global__ __launch_bounds__(256) void k_scatter1(const int* __restrict__ ei,
                                                  const int* __restrict__ bh,
                                                  int* __restrict__ binned) {
  __shared__ int cur[NBINS];
  int t = threadIdx.x;
  cur[t] = bh[t * NB1 + blockIdx.x];
  cur[t + 256] = bh[(t + 256) * NB1 + blockIdx.x];
  __syncthreads();
  const int4* s4p = (const int4*)ei;
  const int4* d4p = (const int4*)(ei + E_EDGES);
  #pragma unroll
  for (int u = 0; u < 4; ++u) {
    int i4 = blockIdx.x * 1024 + u * 256 + t;
    if (i4 < E_EDGES / 4) {
      int4 sv = s4p[i4];
      int4 dv = d4p[i4];
      int p0 = atomicAdd(&cur[dv.x >> 8], 1);
      int p1 = atomicAdd(&cur[dv.y >> 8], 1);
      int p2 = atomicAdd(&cur[dv.z >> 8], 1);
      int p3 = atomicAdd(&cur[dv.w >> 8], 1);
      binned[p0] = sv.x | ((dv.x & 255) << 20);
      binned[p1] = sv.y | ((dv.y & 255) << 20);
      binned[p2] = sv.z | ((dv.z & 255) << 20);
      binned[p3] = sv.w | ((dv.w & 255) << 20);
    }
  }
}

// ---------------- level-2: per-bucket exact CSR (one block per bucket) -------
__global__ __launch_bounds__(256) void k_csr(const int* __restrict__ bh,
                                             const int* __restrict__ binned,
                                             int* __restrict__ offs,
                                             int* __restrict__ srcidx) {
  __shared__ int h[256];
  __shared__ int s[256];
  __shared__ int cur[256];
  int t = threadIdx.x;
  int bin = blockIdx.x;
  int base = bh[bin * NB1];
  int end  = bh[(bin + 1) * NB1];
  h[t] = 0;
  __syncthreads();
  for (int i = base + t; i < end; i += 256)
    atomicAdd(&h[(binned[i] >> 20) & 255], 1);
  __syncthreads();
  s[t] = h[t];
  __syncthreads();
  #pragma unroll
  for (int off = 1; off < 256; off <<= 1) {
    int x = (t >= off) ? s[t - off] : 0;
    __syncthreads();
    s[t] += x;
    __syncthreads();
  }
  int excl = (t > 0) ? s[t - 1] : 0;
  cur[t] = excl;
  int node = bin * 256 + t;
  if (node < N_NODES) offs[node] = base + excl;
  if (node == N_NODES) offs[N_NODES] = E_EDGES;
  __syncthreads();
  for (int i = base + t; i < end; i += 256) {
    int p = binned[i];
    int r = atomicAdd(&cur[(p >> 20) & 255], 1);
    srcidx[base + r] = p & 0xFFFFF;
  }
}

// -------- fused gather+mean+GEMM: out = [mean(nbrs)|h] @ WcatT^T + b_l -------
// 512-thread block = 8 waves; wave gathers 2 nodes (16 outstanding row loads,
// proven structure) -> block owns 16 rows; agg staged in LDS (stride 68 pad:
// 2-way bank alias only); each wave then computes one 16-col MFMA tile.
__global__ __launch_bounds__(512) void k_gathgemm(const unsigned* __restrict__ hb,
                                                  const int* __restrict__ offs,
                                                  const int* __restrict__ srcidx,
                                                  const unsigned* __restrict__ wtb,
                                                  const float* __restrict__ bl,
                                                  float* __restrict__ out) {
  __shared__ unsigned agg[16 * 68];   // 16 rows, stride 68 u32 (272 B, 16B-aligned)
  int wv   = threadIdx.x >> 6;
  int lane = threadIdx.x & 63;
  int r0 = blockIdx.x * 16;
  int n0 = r0 + wv * 2;
  int n1 = n0 + 1;
  int b0 = __builtin_amdgcn_readfirstlane(offs[n0]);
  int e0 = __builtin_amdgcn_readfirstlane(offs[n0 + 1]);
  int b1 = __builtin_amdgcn_readfirstlane(offs[n1]);
  int e1 = __builtin_amdgcn_readfirstlane(offs[n1 + 1]);
  int m0 = e0 - b0, m1 = e1 - b1;
  int c  = (m0 < m1 ? m0 : m1) & ~7;   // common interleaved part

  float ax0 = 0.0f, ay0 = 0.0f, ax1 = 0.0f, ay1 = 0.0f;

  // interleaved: 16 outstanding loads (8 per chain)
  for (int j = 0; j < c; j += 8) {
    unsigned p0[8], p1[8];
    #pragma unroll
    for (int i = 0; i < 8; ++i) {
      int s0 = srcidx[b0 + j + i];
      int s1 = srcidx[b1 + j + i];
      p0[i] = hb[(size_t)s0 * 64 + lane];
      p1[i] = hb[(size_t)s1 * 64 + lane];
    }
    #pragma unroll
    for (int i = 0; i < 8; ++i) {
      float2 v0 = bf16unpack(p0[i]);
      float2 v1 = bf16unpack(p1[i]);
      ax0 += v0.x; ay0 += v0.y;
      ax1 += v1.x; ay1 += v1.y;
    }
  }
  // tail of node 0
  for (int j = b0 + c; j < e0; ) {
    int rem = e0 - j;
    if (rem >= 8) {
      unsigned p[8];
      #pragma unroll
      for (int i = 0; i < 8; ++i) p[i] = hb[(size_t)srcidx[j + i] * 64 + lane];
      #pragma unroll
      for (int i = 0; i < 8; ++i) { float2 v = bf16unpack(p[i]); ax0 += v.x; ay0 += v.y; }
      j += 8;
    } else {
      float2 v = bf16unpack(hb[(size_t)srcidx[j] * 64 + lane]);
      ax0 += v.x; ay0 += v.y;
      ++j;
    }
  }
  // tail of node 1
  for (int j = b1 + c; j < e1; ) {
    int rem = e1 - j;
    if (rem >= 8) {
      unsigned p[8];
      #pragma unroll
      for (int i = 0; i < 8; ++i) p[i] = hb[(size_t)srcidx[j + i] * 64 + lane];
      #pragma unroll
      for (int i = 0; i < 8; ++i) { float2 v = bf16unpack(p[i]); ax1 += v.x; ay1 += v.y; }
      j += 8;
    } else {
      float2 v = bf16unpack(hb[(size_t)srcidx[j] * 64 + lane]);
      ax1 += v.x; ay1 += v.y;
      ++j;
    }
  }

  float inv0 = 1.0f / fmaxf((float)m0, 1.0f);
  float inv1 = 1.0f / fmaxf((float)m1, 1.0f);
  agg[(wv * 2 + 0) * 68 + lane] = bf16pack(ax0 * inv0, ay0 * inv0);
  agg[(wv * 2 + 1) * 68 + lane] = bf16pack(ax1 * inv1, ay1 * inv1);
  __syncthreads();

  // ---- GEMM epilogue: wave wv owns 16-col tile ct = wv ----
  int m = lane & 15;
  int q = lane >> 4;
  int rowA = r0 + m;

  short8 afrag[8];
  #pragma unroll
  for (int kb = 0; kb < 4; ++kb) {             // K 0..127 from agg (LDS)
    uint4 u = *(const uint4*)&agg[m * 68 + (kb * 4 + q) * 4];
    afrag[kb] = *(short8*)&u;
  }
  const uint4* hr = (const uint4*)(hb + (size_t)rowA * 64);
  #pragma unroll
  for (int kb = 0; kb < 4; ++kb) {             // K 128..255 from h (global)
    uint4 u = hr[kb * 4 + q];
    afrag[kb + 4] = *(short8*)&u;
  }

  const uint4* b4 = (const uint4*)wtb;
  int ct = wv;
  int col = ct * 16 + m;
  floatx4 acc = {0.0f, 0.0f, 0.0f, 0.0f};
  #pragma unroll
  for (int kb = 0; kb < 8; ++kb) {
    uint4 u = b4[kb * 512 + col * 4 + q];
    short8 bfrag = *(short8*)&u;
    acc = __builtin_amdgcn_mfma_f32_16x16x32_bf16(afrag[kb], bfrag, acc, 0, 0, 0);
  }
  float bias = bl[col];
  #pragma unroll
  for (int reg = 0; reg < 4; ++reg) {
    int r = r0 + q * 4 + reg;
    out[(size_t)r * DIM + col] = acc[reg] + bias;
  }
}

extern "C" void kernel_launch(void* const* d_in, const int* in_sizes, int n_in,
                              void* d_out, int out_size, void* d_ws, size_t ws_size,
                              hipStream_t stream) {
  const float* x  = (const float*)d_in[0];
  const int*   ei = (const int*)d_in[1];   // [2, E] int32
  const float* lw = (const float*)d_in[2];
  const float* lb = (const float*)d_in[3];
  const float* Wl = (const float*)d_in[4];
  const float* bl = (const float*)d_in[5];
  const float* Wr = (const float*)d_in[6];
  float* out = (float*)d_out;

  char* ws = (char*)d_ws;
  unsigned* hb     = (unsigned*)(ws + HB_OFF);
  unsigned* wtb    = (unsigned*)(ws + WTB_OFF);
  int*      offs   = (int*)(ws + OFFS_OFF);
  int*      bh     = (int*)(ws + BH_OFF);
  int*      bsum   = (int*)(ws + BSUM_OFF);
  int*      binned = (int*)(ws + BIN_OFF);
  int*      srcidx = (int*)(ws + SRC_OFF);

  k_prep<<<N_NODES / 4, 256, 0, stream>>>(x, lw, lb, Wl, Wr, ei, hb, wtb, bh);
  k_hscan1<<<HS_BLOCKS, 256, 0, stream>>>(bh, bsum);
  k_hscan2<<<HS_BLOCKS, 256, 0, stream>>>(bh, bsum);
  k_scatter1<<<NB1, 256, 0, stream>>>(ei, bh, binned);
  k_csr<<<NB1, 256, 0, stream>>>(bh, binned, offs, srcidx);
  k_gathgemm<<<N_NODES / 16, 512, 0, stream>>>(hb, offs, srcidx, wtb, bl, out);
}

// Round 6
// 254.356 us; speedup vs baseline: 3.2810x; 1.0290x over previous
//
#include <hip/hip_runtime.h>

#define N_NODES 100000
#define E_EDGES 1600000
#define DIM     128

// Binning geometry:
//  coarse bucket = 256 nodes (dst>>8): 391 real buckets, padded 512
//  chunk = 8192 edges: 196 chunks
#define NB1     196            // level-1 chunks (8192 edges each)
#define CHUNK   8192
#define NBINS   512            // padded bucket count (actual 391)
#define NBUCKET 391
#define NBH     (NBINS * NB1)  // 100352 bin-major [bin][chunk] histogram entries
#define HS_BLOCKS 98           // NBH / 1024 exactly

// Workspace layout (bytes), total ~39.3 MiB:
#define HB_OFF    0            // h packed bf16: N*64 u32 = 25,600,000
#define WTB_OFF   25600000     // WcatT bf16 B-fragment layout: 16384 u32 = 65,536
#define OFFS_OFF  25665536     // N+1 int (padded to 400,064)
#define BH_OFF    26065600     // NBH ints = 401,408
#define BSUM_OFF  26467008     // 98 ints (padded to 1024)
#define BIN_OFF   26468032     // E ints = 6,400,000
#define SRC_OFF   32868032     // E ints = 6,400,000 -> end 39,268,032

typedef __attribute__((ext_vector_type(8))) short short8;
typedef __attribute__((ext_vector_type(4))) float floatx4;

// ---------- bf16 pack/unpack (RNE) ----------
__device__ __forceinline__ unsigned bf16pack(float a, float b) {
  unsigned ua = __float_as_uint(a); ua += 0x7fffu + ((ua >> 16) & 1u);
  unsigned ub = __float_as_uint(b); ub += 0x7fffu + ((ub >> 16) & 1u);
  return (ua >> 16) | (ub & 0xffff0000u);
}
__device__ __forceinline__ float2 bf16unpack(unsigned p) {
  return make_float2(__uint_as_float(p << 16), __uint_as_float(p & 0xffff0000u));
}

// ------------- prep: LayerNorm+ReLU -> hb, weight pack, level-1 histogram ----
__global__ __launch_bounds__(256) void k_prep(const float* __restrict__ x,
                                              const float* __restrict__ lw,
                                              const float* __restrict__ lb,
                                              const float* __restrict__ Wl,
                                              const float* __restrict__ Wr,
                                              const int* __restrict__ ei,
                                              unsigned* __restrict__ hb,
                                              unsigned* __restrict__ wtb,
                                              int* __restrict__ bh) {
  int gid = blockIdx.x * 256 + threadIdx.x;
  int t = threadIdx.x;

  // --- LN+ReLU ---
  {
    int row  = blockIdx.x * 4 + (t >> 6);
    int lane = t & 63;
    float2 v = ((const float2*)(x + (size_t)row * DIM))[lane];
    float s  = v.x + v.y;
    float sq = v.x * v.x + v.y * v.y;
    #pragma unroll
    for (int off = 32; off > 0; off >>= 1) {
      s  += __shfl_xor(s, off);
      sq += __shfl_xor(sq, off);
    }
    float mu  = s * (1.0f / 128.0f);
    float var = sq * (1.0f / 128.0f) - mu * mu;
    float rs  = rsqrtf(var + 1e-5f);
    float2 w = ((const float2*)lw)[lane];
    float2 b = ((const float2*)lb)[lane];
    float ox = fmaxf((v.x - mu) * rs * w.x + b.x, 0.0f);
    float oy = fmaxf((v.y - mu) * rs * w.y + b.y, 0.0f);
    hb[(size_t)row * 64 + lane] = bf16pack(ox, oy);
  }

  // --- weight pack (bf16, B-fragment layout) ---
  if (gid < 16384) {
    int j2 = gid & 3;
    int q  = (gid >> 2) & 3;
    int c  = (gid >> 4) & 127;
    int kb = gid >> 11;
    int k0 = kb * 32 + q * 8 + j2 * 2;
    int k1 = k0 + 1;
    float v0 = (k0 < 128) ? Wl[c * 128 + k0] : Wr[c * 128 + (k0 - 128)];
    float v1 = (k1 < 128) ? Wl[c * 128 + k1] : Wr[c * 128 + (k1 - 128)];
    wtb[gid] = bf16pack(v0, v1);
  }

  // --- level-1 histogram: chunk = 8192 edges (block-uniform branch) ---
  if (blockIdx.x < NB1) {
    __shared__ int h[NBINS];
    h[t] = 0; h[t + 256] = 0;
    __syncthreads();
    const int4* d4p = (const int4*)(ei + E_EDGES);
    #pragma unroll
    for (int u = 0; u < 8; ++u) {
      int i4 = blockIdx.x * (CHUNK / 4) + u * 256 + t;
      if (i4 < E_EDGES / 4) {
        int4 d = d4p[i4];
        atomicAdd(&h[d.x >> 8], 1);
        atomicAdd(&h[d.y >> 8], 1);
        atomicAdd(&h[d.z >> 8], 1);
        atomicAdd(&h[d.w >> 8], 1);
      }
    }
    __syncthreads();
    bh[t * NB1 + blockIdx.x] = h[t];
    bh[(t + 256) * NB1 + blockIdx.x] = h[t + 256];
  }
}

// ---------------- scan stage 1 over bh (in-place, 1024 elems/block) ----------
__global__ __launch_bounds__(256) void k_hscan1(int* __restrict__ bh,
                                                int* __restrict__ bsum) {
  __shared__ int s[256];
  int t = threadIdx.x;
  int base = blockIdx.x * 1024 + t * 4;
  int a0 = (base + 0 < NBH) ? bh[base + 0] : 0;
  int a1 = (base + 1 < NBH) ? bh[base + 1] : 0;
  int a2 = (base + 2 < NBH) ? bh[base + 2] : 0;
  int a3 = (base + 3 < NBH) ? bh[base + 3] : 0;
  s[t] = a0 + a1 + a2 + a3;
  __syncthreads();
  #pragma unroll
  for (int off = 1; off < 256; off <<= 1) {
    int x = (t >= off) ? s[t - off] : 0;
    __syncthreads();
    s[t] += x;
    __syncthreads();
  }
  int excl = (t > 0) ? s[t - 1] : 0;
  if (t == 255) bsum[blockIdx.x] = s[255];
  if (base + 0 < NBH) bh[base + 0] = excl;
  if (base + 1 < NBH) bh[base + 1] = excl + a0;
  if (base + 2 < NBH) bh[base + 2] = excl + a0 + a1;
  if (base + 3 < NBH) bh[base + 3] = excl + a0 + a1 + a2;
}

// ---------------- scan stage 2: add block bases (98 <= 256 lanes) ------------
__global__ __launch_bounds__(256) void k_hscan2(int* __restrict__ bh,
                                                const int* __restrict__ bsum) {
  __shared__ int s[256];
  int t = threadIdx.x;
  s[t] = (t < HS_BLOCKS) ? bsum[t] : 0;
  __syncthreads();
  #pragma unroll
  for (int off = 1; off < 256; off <<= 1) {
    int x = (t >= off) ? s[t - off] : 0;
    __syncthreads();
    s[t] += x;
    __syncthreads();
  }
  int blk = blockIdx.x;
  int add = (blk > 0) ? s[blk - 1] : 0;
  #pragma unroll
  for (int u = 0; u < 4; ++u) {
    int i = blk * 1024 + t * 4 + u;
    if (i < NBH) bh[i] += add;
  }
}

// ------- level-1 bin-sort: LDS-sorted chunk, COALESCED write-out -------------
// Replaces the random 4B global scatter (cross-XCD line churn, ~150us) with:
//  pass1 LDS hist -> LDS scan -> pass2 place into stage[]+addr[] -> stream out.
// Runs within a bin are contiguous (avg ~21 edges = 84B bursts).
__global__ __launch_bounds__(256) void k_binsort(const int* __restrict__ ei,
                                                 const int* __restrict__ bh,
                                                 int* __restrict__ binned) {
  __shared__ int stage[CHUNK];   // 32 KiB: bin-sorted packed edges
  __shared__ int addr[CHUNK];    // 32 KiB: final global index per staged edge
  __shared__ int hist[NBINS];
  __shared__ int ebase[NBINS];   // intra-chunk exclusive base per bin
  __shared__ int cur[NBINS];     // placement cursor
  __shared__ int gbase[NBINS];   // global base per (bin, chunk) from scanned bh
  __shared__ int s[256];
  int t  = threadIdx.x;
  int ch = blockIdx.x;

  hist[t] = 0; hist[t + 256] = 0;
  gbase[t] = bh[t * NB1 + ch];
  gbase[t + 256] = bh[(t + 256) * NB1 + ch];
  __syncthreads();

  const int4* s4p = (const int4*)ei;
  const int4* d4p = (const int4*)(ei + E_EDGES);

  // pass 1: count
  #pragma unroll
  for (int u = 0; u < 8; ++u) {
    int i4 = ch * (CHUNK / 4) + u * 256 + t;
    if (i4 < E_EDGES / 4) {
      int4 d = d4p[i4];
      atomicAdd(&hist[d.x >> 8], 1);
      atomicAdd(&hist[d.y >> 8], 1);
      atomicAdd(&hist[d.z >> 8], 1);
      atomicAdd(&hist[d.w >> 8], 1);
    }
  }
  __syncthreads();

  // scan 512 bins via 256 pair-partials
  int h0 = hist[2 * t], h1 = hist[2 * t + 1];
  s[t] = h0 + h1;
  __syncthreads();
  #pragma unroll
  for (int off = 1; off < 256; off <<= 1) {
    int xv = (t >= off) ? s[t - off] : 0;
    __syncthreads();
    s[t] += xv;
    __syncthreads();
  }
  int ex = (t > 0) ? s[t - 1] : 0;
  ebase[2 * t] = ex;
  ebase[2 * t + 1] = ex + h0;
  cur[2 * t] = ex;
  cur[2 * t + 1] = ex + h0;
  __syncthreads();

  // pass 2: place edges bin-sorted into LDS, record final global address
  #pragma unroll
  for (int u = 0; u < 8; ++u) {
    int i4 = ch * (CHUNK / 4) + u * 256 + t;
    if (i4 < E_EDGES / 4) {
      int4 sv = s4p[i4];
      int4 dv = d4p[i4];
      {
        int bin = dv.x >> 8; int pos = atomicAdd(&cur[bin], 1);
        stage[pos] = sv.x | ((dv.x & 255) << 20);
        addr[pos]  = gbase[bin] + (pos - ebase[bin]);
      }
      {
        int bin = dv.y >> 8; int pos = atomicAdd(&cur[bin], 1);
        stage[pos] = sv.y | ((dv.y & 255) << 20);
        addr[pos]  = gbase[bin] + (pos - ebase[bin]);
      }
      {
        int bin = dv.z >> 8; int pos = atomicAdd(&cur[bin], 1);
        stage[pos] = sv.z | ((dv.z & 255) << 20);
        addr[pos]  = gbase[bin] + (pos - ebase[bin]);
      }
      {
        int bin = dv.w >> 8; int pos = atomicAdd(&cur[bin], 1);
        stage[pos] = sv.w | ((dv.w & 255) << 20);
        addr[pos]  = gbase[bin] + (pos - ebase[bin]);
      }
    }
  }
  __syncthreads();

  // write-out: mostly-consecutive addresses (contiguous runs per bin)
  int cbase = ch * CHUNK;
  int cnt = E_EDGES - cbase;
  if (cnt > CHUNK) cnt = CHUNK;
  for (int i = t; i < cnt; i += 256)
    binned[addr[i]] = stage[i];
}

// ---------------- level-2: per-bucket exact CSR (one block per bucket) -------
__global__ __launch_bounds__(256) void k_csr(const int* __restrict__ bh,
                                             const int* __restrict__ binned,
                                             int* __restrict__ offs,
                                             int* __restrict__ srcidx) {
  __shared__ int h[256];
  __shared__ int s[256];
  __shared__ int cur[256];
  int t = threadIdx.x;
  int bin = blockIdx.x;
  int base = bh[bin * NB1];
  int end  = bh[(bin + 1) * NB1];
  h[t] = 0;
  __syncthreads();
  for (int i = base + t; i < end; i += 256)
    atomicAdd(&h[(binned[i] >> 20) & 255], 1);
  __syncthreads();
  s[t] = h[t];
  __syncthreads();
  #pragma unroll
  for (int off = 1; off < 256; off <<= 1) {
    int x = (t >= off) ? s[t - off] : 0;
    __syncthreads();
    s[t] += x;
    __syncthreads();
  }
  int excl = (t > 0) ? s[t - 1] : 0;
  cur[t] = excl;
  int node = bin * 256 + t;
  if (node < N_NODES) offs[node] = base + excl;
  if (node == N_NODES) offs[N_NODES] = E_EDGES;
  __syncthreads();
  for (int i = base + t; i < end; i += 256) {
    int p = binned[i];
    int r = atomicAdd(&cur[(p >> 20) & 255], 1);
    srcidx[base + r] = p & 0xFFFFF;
  }
}

// -------- fused gather+mean+GEMM: out = [mean(nbrs)|h] @ WcatT^T + b_l -------
__global__ __launch_bounds__(512) void k_gathgemm(const unsigned* __restrict__ hb,
                                                  const int* __restrict__ offs,
                                                  const int* __restrict__ srcidx,
                                                  const unsigned* __restrict__ wtb,
                                                  const float* __restrict__ bl,
                                                  float* __restrict__ out) {
  __shared__ unsigned agg[16 * 68];   // 16 rows, stride 68 u32 (2-way bank alias only)
  int wv   = threadIdx.x >> 6;
  int lane = threadIdx.x & 63;
  int r0 = blockIdx.x * 16;
  int n0 = r0 + wv * 2;
  int n1 = n0 + 1;
  int b0 = __builtin_amdgcn_readfirstlane(offs[n0]);
  int e0 = __builtin_amdgcn_readfirstlane(offs[n0 + 1]);
  int b1 = __builtin_amdgcn_readfirstlane(offs[n1]);
  int e1 = __builtin_amdgcn_readfirstlane(offs[n1 + 1]);
  int m0 = e0 - b0, m1 = e1 - b1;
  int c  = (m0 < m1 ? m0 : m1) & ~7;   // common interleaved part

  float ax0 = 0.0f, ay0 = 0.0f, ax1 = 0.0f, ay1 = 0.0f;

  for (int j = 0; j < c; j += 8) {
    unsigned p0[8], p1[8];
    #pragma unroll
    for (int i = 0; i < 8; ++i) {
      int s0 = srcidx[b0 + j + i];
      int s1 = srcidx[b1 + j + i];
      p0[i] = hb[(size_t)s0 * 64 + lane];
      p1[i] = hb[(size_t)s1 * 64 + lane];
    }
    #pragma unroll
    for (int i = 0; i < 8; ++i) {
      float2 v0 = bf16unpack(p0[i]);
      float2 v1 = bf16unpack(p1[i]);
      ax0 += v0.x; ay0 += v0.y;
      ax1 += v1.x; ay1 += v1.y;
    }
  }
  for (int j = b0 + c; j < e0; ) {
    int rem = e0 - j;
    if (rem >= 8) {
      unsigned p[8];
      #pragma unroll
      for (int i = 0; i < 8; ++i) p[i] = hb[(size_t)srcidx[j + i] * 64 + lane];
      #pragma unroll
      for (int i = 0; i < 8; ++i) { float2 v = bf16unpack(p[i]); ax0 += v.x; ay0 += v.y; }
      j += 8;
    } else {
      float2 v = bf16unpack(hb[(size_t)srcidx[j] * 64 + lane]);
      ax0 += v.x; ay0 += v.y;
      ++j;
    }
  }
  for (int j = b1 + c; j < e1; ) {
    int rem = e1 - j;
    if (rem >= 8) {
      unsigned p[8];
      #pragma unroll
      for (int i = 0; i < 8; ++i) p[i] = hb[(size_t)srcidx[j + i] * 64 + lane];
      #pragma unroll
      for (int i = 0; i < 8; ++i) { float2 v = bf16unpack(p[i]); ax1 += v.x; ay1 += v.y; }
      j += 8;
    } else {
      float2 v = bf16unpack(hb[(size_t)srcidx[j] * 64 + lane]);
      ax1 += v.x; ay1 += v.y;
      ++j;
    }
  }

  float inv0 = 1.0f / fmaxf((float)m0, 1.0f);
  float inv1 = 1.0f / fmaxf((float)m1, 1.0f);
  agg[(wv * 2 + 0) * 68 + lane] = bf16pack(ax0 * inv0, ay0 * inv0);
  agg[(wv * 2 + 1) * 68 + lane] = bf16pack(ax1 * inv1, ay1 * inv1);
  __syncthreads();

  // ---- GEMM epilogue: wave wv owns 16-col tile ----
  int m = lane & 15;
  int q = lane >> 4;
  int rowA = r0 + m;

  short8 afrag[8];
  #pragma unroll
  for (int kb = 0; kb < 4; ++kb) {             // K 0..127 from agg (LDS)
    uint4 u = *(const uint4*)&agg[m * 68 + (kb * 4 + q) * 4];
    afrag[kb] = *(short8*)&u;
  }
  const uint4* hr = (const uint4*)(hb + (size_t)rowA * 64);
  #pragma unroll
  for (int kb = 0; kb < 4; ++kb) {             // K 128..255 from h (global)
    uint4 u = hr[kb * 4 + q];
    afrag[kb + 4] = *(short8*)&u;
  }

  const uint4* b4 = (const uint4*)wtb;
  int col = wv * 16 + m;
  floatx4 acc = {0.0f, 0.0f, 0.0f, 0.0f};
  #pragma unroll
  for (int kb = 0; kb < 8; ++kb) {
    uint4 u = b4[kb * 512 + col * 4 + q];
    short8 bfrag = *(short8*)&u;
    acc = __builtin_amdgcn_mfma_f32_16x16x32_bf16(afrag[kb], bfrag, acc, 0, 0, 0);
  }
  float bias = bl[col];
  #pragma unroll
  for (int reg = 0; reg < 4; ++reg) {
    int r = r0 + q * 4 + reg;
    out[(size_t)r * DIM + col] = acc[reg] + bias;
  }
}

extern "C" void kernel_launch(void* const* d_in, const int* in_sizes, int n_in,
                              void* d_out, int out_size, void* d_ws, size_t ws_size,
                              hipStream_t stream) {
  const float* x  = (const float*)d_in[0];
  const int*   ei = (const int*)d_in[1];   // [2, E] int32
  const float* lw = (const float*)d_in[2];
  const float* lb = (const float*)d_in[3];
  const float* Wl = (const float*)d_in[4];
  const float* bl = (const float*)d_in[5];
  const float* Wr = (const float*)d_in[6];
  float* out = (float*)d_out;

  char* ws = (char*)d_ws;
  unsigned* hb     = (unsigned*)(ws + HB_OFF);
  unsigned* wtb    = (unsigned*)(ws + WTB_OFF);
  int*      offs   = (int*)(ws + OFFS_OFF);
  int*      bh     = (int*)(ws + BH_OFF);
  int*      bsum   = (int*)(ws + BSUM_OFF);
  int*      binned = (int*)(ws + BIN_OFF);
  int*      srcidx = (int*)(ws + SRC_OFF);

  k_prep<<<N_NODES / 4, 256, 0, stream>>>(x, lw, lb, Wl, Wr, ei, hb, wtb, bh);
  k_hscan1<<<HS_BLOCKS, 256, 0, stream>>>(bh, bsum);
  k_hscan2<<<HS_BLOCKS, 256, 0, stream>>>(bh, bsum);
  k_binsort<<<NB1, 256, 0, stream>>>(ei, bh, binned);
  k_csr<<<NBUCKET, 256, 0, stream>>>(bh, binned, offs, srcidx);
  k_gathgemm<<<N_NODES / 16, 512, 0, stream>>>(hb, offs, srcidx, wtb, bl, out);
}